// Round 8
// baseline (301.226 us; speedup 1.0000x reference)
//
#include <hip/hip_runtime.h>
#include <hip/hip_fp16.h>
#include <math.h>

#define NN 50000
#define EE 800000
#define ET (EE + NN)
#define FIN 256
#define CCOUT 128
#define HH 2
#define HC 256
#define NEG 0.2f

#define NB_EDGE ((ET + 255) / 256)
#define NB_SCAN ((NN + 255) / 256)
#define NB_XPREP (NN / 4)

// prep grid: 1 detect + 2 watt + 64 W-conv (16384 float4 groups) + 32 linw-conv (8192 groups)
#define PREP_W_BLOCKS 64
#define PREP_LW_BLOCKS 32
#define PREP_GRID (3 + PREP_W_BLOCKS + PREP_LW_BLOCKS)

typedef __attribute__((ext_vector_type(8))) short short8;
typedef __attribute__((ext_vector_type(4))) float floatx4;

// ---------------- bf16 helpers ----------------
__device__ __forceinline__ unsigned short f2bf(float f)
{
    union { float f; unsigned int u; } x; x.f = f;
    unsigned int r = x.u + 0x7fffu + ((x.u >> 16) & 1u);   // RNE
    return (unsigned short)(r >> 16);
}
__device__ __forceinline__ float bf2f(unsigned short u)
{
    union { unsigned int u; float f; } x; x.u = ((unsigned int)u) << 16;
    return x.f;
}
// bf16 pair unpack from u32 (low/high half) — no dynamic indexing (see R5 note)
__device__ __forceinline__ float bf_lo(unsigned int u)
{
    union { unsigned int u; float f; } x; x.u = u << 16;
    return x.f;
}
__device__ __forceinline__ float bf_hi(unsigned int u)
{
    union { unsigned int u; float f; } x; x.u = u & 0xffff0000u;
    return x.f;
}
// fp16 (bits) -> fp32
__device__ __forceinline__ float h2f_bits(unsigned short u)
{
    __half h = *(const __half*)&u;
    return __half2float(h);
}

__device__ __forceinline__ int load_idx(const int* ei32, int is64, int pos)
{
    return is64 ? ei32[2 * pos] : ei32[pos];
}

// ---------------- fused prep: detect + watt + weight bf16 conversion ----------------
__global__ __launch_bounds__(256) void prep_kernel(const float* __restrict__ W,
                                                   const float* __restrict__ att_s,
                                                   const float* __restrict__ att_d,
                                                   const float* __restrict__ lin_w,
                                                   const int* __restrict__ ei32,
                                                   float* __restrict__ was,
                                                   float* __restrict__ wad,
                                                   unsigned short* __restrict__ Wb,
                                                   unsigned short* __restrict__ linwb,
                                                   int* __restrict__ flag)
{
    int b = blockIdx.x, t = threadIdx.x;
    if (b == 0) {
        if (t < 64) {
            int v = ei32[2 * t + 1];
            unsigned long long m = __ballot(v != 0);
            if (t == 0) *flag = (m == 0ull) ? 1 : 0;
        }
    } else if (b <= 2) {
        int hd = b - 1;
        float as = 0.f, ad = 0.f;
        for (int c = 0; c < CCOUT; c++) {
            float wv = W[(size_t)(hd * CCOUT + c) * FIN + t];
            as += att_s[hd * CCOUT + c] * wv;
            ad += att_d[hd * CCOUT + c] * wv;
        }
        was[hd * FIN + t] = as;
        wad[hd * FIN + t] = ad;
    } else if (b < 3 + PREP_W_BLOCKS) {
        int i = (b - 3) * 256 + t;
        float4 v = *(const float4*)(W + (size_t)i * 4);
        ushort4 o;
        o.x = f2bf(v.x); o.y = f2bf(v.y); o.z = f2bf(v.z); o.w = f2bf(v.w);
        *(ushort4*)(Wb + (size_t)i * 4) = o;
    } else {
        int i = (b - 3 - PREP_W_BLOCKS) * 256 + t;
        float4 v = *(const float4*)(lin_w + (size_t)i * 4);
        ushort4 o;
        o.x = f2bf(v.x); o.y = f2bf(v.y); o.z = f2bf(v.z); o.w = f2bf(v.w);
        *(ushort4*)(linwb + (size_t)i * 4) = o;
    }
}

// ---------------- fused: x->bf16 + fp32 attention logits || degree count ----------------
// count half: fire-and-forget atomicAdd (NO return value -> no vmcnt stall; m20:
// return-less atomicAdd compiles to global_atomic_add without sc0). Edge order
// within a CSR row is established later by scatter's cursor atomic.
__global__ __launch_bounds__(256) void xprep_count_kernel(const float* __restrict__ x,
                                                          const float* __restrict__ was,
                                                          const float* __restrict__ wad,
                                                          unsigned short* __restrict__ xb,
                                                          float* __restrict__ a_s,
                                                          float* __restrict__ a_d,
                                                          const int* __restrict__ ei32,
                                                          const int* __restrict__ flag,
                                                          int* __restrict__ deg)
{
    int b = blockIdx.x, t = threadIdx.x;
    if (b < NB_XPREP) {
        int w = t >> 6, l = t & 63;
        int n = b * 4 + w;
        float4 xv = *(const float4*)(x + (size_t)n * FIN + l * 4);
        ushort4 xs;
        xs.x = f2bf(xv.x); xs.y = f2bf(xv.y); xs.z = f2bf(xv.z); xs.w = f2bf(xv.w);
        *(ushort4*)(xb + (size_t)n * FIN + l * 4) = xs;

        float4 s0 = *(const float4*)(was + l * 4);
        float4 s1 = *(const float4*)(was + FIN + l * 4);
        float4 d0 = *(const float4*)(wad + l * 4);
        float4 d1 = *(const float4*)(wad + FIN + l * 4);
        float vs0 = xv.x * s0.x + xv.y * s0.y + xv.z * s0.z + xv.w * s0.w;
        float vs1 = xv.x * s1.x + xv.y * s1.y + xv.z * s1.z + xv.w * s1.w;
        float vd0 = xv.x * d0.x + xv.y * d0.y + xv.z * d0.z + xv.w * d0.w;
        float vd1 = xv.x * d1.x + xv.y * d1.y + xv.z * d1.z + xv.w * d1.w;
#pragma unroll
        for (int off = 32; off > 0; off >>= 1) {
            vs0 += __shfl_down(vs0, off);
            vs1 += __shfl_down(vs1, off);
            vd0 += __shfl_down(vd0, off);
            vd1 += __shfl_down(vd1, off);
        }
        if (l == 0) {
            a_s[n * 2 + 0] = vs0; a_s[n * 2 + 1] = vs1;
            a_d[n * 2 + 0] = vd0; a_d[n * 2 + 1] = vd1;
        }
    } else {
        int e = (b - NB_XPREP) * 256 + t;
        if (e < ET) {
            int is64 = *flag;
            int d = (e < EE) ? load_idx(ei32, is64, EE + e) : (e - EE);
            atomicAdd(&deg[d], 1);   // fire-and-forget
        }
    }
}

// ---------------- MFMA bf16 GEMM: C[M,N] = A[M,K] @ B[N,K]^T (+bias) ----------------
template <bool ADD_BIAS, bool OUT_BF16>
__global__ __launch_bounds__(256) void gemm_mfma(const unsigned short* __restrict__ A,
                                                 const unsigned short* __restrict__ B,
                                                 const float* __restrict__ bias,
                                                 void* __restrict__ Cout,
                                                 int M, int N, int K)
{
    const int LDT = 40;
    __shared__ unsigned short As[128 * LDT];
    __shared__ unsigned short Bs[128 * LDT];

    int tid = threadIdx.x;
    int wave = tid >> 6, lane = tid & 63;
    int wr = wave >> 1, wc = wave & 1;
    int quad = lane >> 4, l16 = lane & 15;
    int bm0 = blockIdx.x * 128;
    int bn0 = blockIdx.y * 128;

    floatx4 acc[4][4] = {};

    for (int kk = 0; kk < K; kk += 32) {
#pragma unroll
        for (int p = 0; p < 2; p++) {
            int idx = p * 256 + tid;
            int row = idx >> 2, seg = idx & 3;
            int grow = bm0 + row; if (grow >= M) grow = M - 1;
            uint4 va = *(const uint4*)(A + (size_t)grow * K + kk + seg * 8);
            *(uint4*)(&As[row * LDT + seg * 8]) = va;
            uint4 vb = *(const uint4*)(B + (size_t)(bn0 + row) * K + kk + seg * 8);
            *(uint4*)(&Bs[row * LDT + seg * 8]) = vb;
        }
        __syncthreads();

        short8 af[4], bfr[4];
#pragma unroll
        for (int mi = 0; mi < 4; mi++)
            af[mi] = *(const short8*)(&As[(wr * 64 + mi * 16 + l16) * LDT + quad * 8]);
#pragma unroll
        for (int ni = 0; ni < 4; ni++)
            bfr[ni] = *(const short8*)(&Bs[(wc * 64 + ni * 16 + l16) * LDT + quad * 8]);
#pragma unroll
        for (int mi = 0; mi < 4; mi++)
#pragma unroll
            for (int ni = 0; ni < 4; ni++)
                acc[mi][ni] = __builtin_amdgcn_mfma_f32_16x16x32_bf16(af[mi], bfr[ni], acc[mi][ni], 0, 0, 0);
        __syncthreads();
    }

#pragma unroll
    for (int mi = 0; mi < 4; mi++) {
#pragma unroll
        for (int ni = 0; ni < 4; ni++) {
            int col = bn0 + wc * 64 + ni * 16 + l16;
#pragma unroll
            for (int r = 0; r < 4; r++) {
                int row = bm0 + wr * 64 + mi * 16 + quad * 4 + r;
                if (row < M) {
                    float v = acc[mi][ni][r];
                    if (ADD_BIAS) v += bias[col];
                    if (OUT_BF16)
                        ((unsigned short*)Cout)[(size_t)row * N + col] = f2bf(v);
                    else
                        ((float*)Cout)[(size_t)row * N + col] = v;
                }
            }
        }
    }
}

// ---------------- scan1: per-block inclusive scan + block totals ----------------
__global__ __launch_bounds__(256) void scan1(const int* __restrict__ deg,
                                             int* __restrict__ tmp, int* __restrict__ bsum)
{
    __shared__ int s[256];
    int i = blockIdx.x * 256 + threadIdx.x;
    int v = (i < NN) ? deg[i] : 0;
    s[threadIdx.x] = v;
    __syncthreads();
    for (int off = 1; off < 256; off <<= 1) {
        int add = (threadIdx.x >= off) ? s[threadIdx.x - off] : 0;
        __syncthreads();
        s[threadIdx.x] += add;
        __syncthreads();
    }
    if (i < NN) tmp[i] = s[threadIdx.x];
    if (threadIdx.x == 255) bsum[blockIdx.x] = s[255];
}

// ---------------- scan2+scan3 fused: each block redundantly reduces its bsum prefix ----------------
__global__ __launch_bounds__(256) void scan23(const int* __restrict__ deg,
                                              const int* __restrict__ tmp,
                                              const int* __restrict__ bsum,
                                              int* __restrict__ rowstart)
{
    __shared__ int s[256];
    int b = blockIdx.x, t = threadIdx.x;
    int v = (t < NB_SCAN && t < b) ? bsum[t] : 0;
    s[t] = v;
    __syncthreads();
#pragma unroll
    for (int off = 128; off > 0; off >>= 1) {
        if (t < off) s[t] += s[t + off];
        __syncthreads();
    }
    int offset = s[0];
    int i = b * 256 + t;
    if (i < NN) rowstart[i] = tmp[i] - deg[i] + offset;
    if (i == 0) rowstart[NN] = ET;
}

// ---------------- CSR build: cursor atomic (with return) + packed 8B record {src, half2 p} ----
__global__ void scatter_kernel(const int* __restrict__ ei32, const int* __restrict__ flag,
                               const int* __restrict__ rowstart,
                               int* __restrict__ cursor,
                               const float* __restrict__ a_s,
                               const float* __restrict__ a_d,
                               uint2* __restrict__ rec)
{
    int e = blockIdx.x * blockDim.x + threadIdx.x;
    if (e >= ET) return;
    int is64 = *flag;
    int s, d;
    if (e < EE) { s = load_idx(ei32, is64, e); d = load_idx(ei32, is64, EE + e); }
    else { s = d = e - EE; }
    float e0 = a_s[s * 2 + 0] + a_d[d * 2 + 0];
    float e1 = a_s[s * 2 + 1] + a_d[d * 2 + 1];
    e0 = e0 > 0.f ? e0 : NEG * e0;
    e1 = e1 > 0.f ? e1 : NEG * e1;
    __half2 hp = __floats2half2_rn(__expf(e0), __expf(e1));
    uint2 r;
    r.x = (unsigned int)s;
    r.y = *(unsigned int*)&hp;
    int j = rowstart[d] + atomicAdd(&cursor[d], 1);
    rec[j] = r;
}

// ---------------- gather-aggregate: wave-per-node, 2 edges/wave (half-wave each, 16B loads) ----
// lane layout: half = lane>>5 selects edge slot; l = lane&31 covers channels l*8..l*8+7
// (uint4 = 16 B = 8 bf16); head = l>>4. Cross-half combine via shfl_xor(...,32) at the end.
// NOTE: no dynamic register indexing (R5: compiler spills via LDS scratch).
__global__ __launch_bounds__(256) void agg6_kernel(const unsigned short* __restrict__ hb,
                                                   const int* __restrict__ rowstart,
                                                   const uint2* __restrict__ rec,
                                                   const float* __restrict__ bias,
                                                   unsigned short* __restrict__ aggb)
{
    int wave = threadIdx.x >> 6, lane = threadIdx.x & 63;
    int d = blockIdx.x * 4 + wave;
    int half = lane >> 5;
    int l = lane & 31;
    int hshift = (l >> 4) << 4;          // 0 for ch 0..127 (head 0), 16 for ch 128..255
    int c = l * 8;
    int j0 = rowstart[d], j1 = rowstart[d + 1];

    float a0 = 0.f, a1 = 0.f, a2 = 0.f, a3 = 0.f;
    float a4 = 0.f, a5 = 0.f, a6 = 0.f, a7 = 0.f;
    float psum = 0.f;

    int j = j0 + half;
    for (; j + 2 < j1; j += 4) {
        uint2 r0 = rec[j], r1 = rec[j + 2];
        float p0 = h2f_bits((unsigned short)(r0.y >> hshift));
        float p1 = h2f_bits((unsigned short)(r1.y >> hshift));
        psum += p0 + p1;
        uint4 h0 = *(const uint4*)(hb + (size_t)r0.x * HC + c);
        uint4 h1 = *(const uint4*)(hb + (size_t)r1.x * HC + c);
        a0 += p0 * bf_lo(h0.x) + p1 * bf_lo(h1.x);
        a1 += p0 * bf_hi(h0.x) + p1 * bf_hi(h1.x);
        a2 += p0 * bf_lo(h0.y) + p1 * bf_lo(h1.y);
        a3 += p0 * bf_hi(h0.y) + p1 * bf_hi(h1.y);
        a4 += p0 * bf_lo(h0.z) + p1 * bf_lo(h1.z);
        a5 += p0 * bf_hi(h0.z) + p1 * bf_hi(h1.z);
        a6 += p0 * bf_lo(h0.w) + p1 * bf_lo(h1.w);
        a7 += p0 * bf_hi(h0.w) + p1 * bf_hi(h1.w);
    }
    for (; j < j1; j += 2) {
        uint2 r0 = rec[j];
        float p0 = h2f_bits((unsigned short)(r0.y >> hshift));
        psum += p0;
        uint4 h0 = *(const uint4*)(hb + (size_t)r0.x * HC + c);
        a0 += p0 * bf_lo(h0.x);
        a1 += p0 * bf_hi(h0.x);
        a2 += p0 * bf_lo(h0.y);
        a3 += p0 * bf_hi(h0.y);
        a4 += p0 * bf_lo(h0.z);
        a5 += p0 * bf_hi(h0.z);
        a6 += p0 * bf_lo(h0.w);
        a7 += p0 * bf_hi(h0.w);
    }

    a0 += __shfl_xor(a0, 32);
    a1 += __shfl_xor(a1, 32);
    a2 += __shfl_xor(a2, 32);
    a3 += __shfl_xor(a3, 32);
    a4 += __shfl_xor(a4, 32);
    a5 += __shfl_xor(a5, 32);
    a6 += __shfl_xor(a6, 32);
    a7 += __shfl_xor(a7, 32);
    psum += __shfl_xor(psum, 32);

    if (half == 0) {
        float inv = 1.f / fmaxf(psum, 1e-16f);
        float4 b0 = *(const float4*)(bias + c);
        float4 b1 = *(const float4*)(bias + c + 4);
        float v0 = a0 * inv + b0.x;
        float v1 = a1 * inv + b0.y;
        float v2 = a2 * inv + b0.z;
        float v3 = a3 * inv + b0.w;
        float v4 = a4 * inv + b1.x;
        float v5 = a5 * inv + b1.y;
        float v6 = a6 * inv + b1.z;
        float v7 = a7 * inv + b1.w;
        v0 = v0 > 0.f ? v0 : expm1f(v0);
        v1 = v1 > 0.f ? v1 : expm1f(v1);
        v2 = v2 > 0.f ? v2 : expm1f(v2);
        v3 = v3 > 0.f ? v3 : expm1f(v3);
        v4 = v4 > 0.f ? v4 : expm1f(v4);
        v5 = v5 > 0.f ? v5 : expm1f(v5);
        v6 = v6 > 0.f ? v6 : expm1f(v6);
        v7 = v7 > 0.f ? v7 : expm1f(v7);
        uint4 o;
        o.x = (unsigned int)f2bf(v0) | ((unsigned int)f2bf(v1) << 16);
        o.y = (unsigned int)f2bf(v2) | ((unsigned int)f2bf(v3) << 16);
        o.z = (unsigned int)f2bf(v4) | ((unsigned int)f2bf(v5) << 16);
        o.w = (unsigned int)f2bf(v6) | ((unsigned int)f2bf(v7) << 16);
        *(uint4*)(aggb + (size_t)d * HC + c) = o;
    }
}

// ---------------- launch ----------------
extern "C" void kernel_launch(void* const* d_in, const int* in_sizes, int n_in,
                              void* d_out, int out_size, void* d_ws, size_t ws_size,
                              hipStream_t stream)
{
    const float* x       = (const float*)d_in[0];
    const int*   ei32    = (const int*)d_in[1];
    const float* W       = (const float*)d_in[2];
    const float* att_src = (const float*)d_in[3];
    const float* att_dst = (const float*)d_in[4];
    const float* bias    = (const float*)d_in[5];
    const float* lin_w   = (const float*)d_in[6];
    const float* lin_b   = (const float*)d_in[7];
    float* out = (float*)d_out;

    char* ws = (char*)d_ws;
    size_t off = 0;
    auto alloc = [&](size_t bytes) -> void* {
        void* p = ws + off;
        off += (bytes + 255) & ~(size_t)255;
        return p;
    };

    // zero-init region first (deg + cursor)
    int*   deg    = (int*)alloc((size_t)NN * 4);
    int*   cursor = (int*)alloc((size_t)NN * 4);
    size_t zero_bytes = off;

    int*   flag     = (int*)alloc(256);
    int*   tmp      = (int*)alloc((size_t)NN * 4);
    int*   bsum     = (int*)alloc(1024);
    int*   rowstart = (int*)alloc((size_t)(NN + 1) * 4);
    float* was      = (float*)alloc((size_t)HH * FIN * 4);
    float* wad      = (float*)alloc((size_t)HH * FIN * 4);
    float* a_s      = (float*)alloc((size_t)NN * 2 * 4);
    float* a_d      = (float*)alloc((size_t)NN * 2 * 4);
    uint2* rec      = (uint2*)alloc((size_t)ET * 8);
    unsigned short* xb     = (unsigned short*)alloc((size_t)NN * FIN * 2);
    unsigned short* Wb     = (unsigned short*)alloc((size_t)HC * FIN * 2);
    unsigned short* linwb  = (unsigned short*)alloc((size_t)CCOUT * HC * 2);
    unsigned short* hb     = (unsigned short*)alloc((size_t)NN * HC * 2);
    unsigned short* aggb   = (unsigned short*)alloc((size_t)NN * HC * 2);

    hipMemsetAsync(d_ws, 0, zero_bytes, stream);

    prep_kernel<<<PREP_GRID, 256, 0, stream>>>(W, att_src, att_dst, lin_w, ei32,
                                               was, wad, Wb, linwb, flag);

    xprep_count_kernel<<<NB_XPREP + NB_EDGE, 256, 0, stream>>>(x, was, wad, xb, a_s, a_d,
                                                               ei32, flag, deg);

    scan1<<<NB_SCAN, 256, 0, stream>>>(deg, tmp, bsum);
    scan23<<<NB_SCAN, 256, 0, stream>>>(deg, tmp, bsum, rowstart);

    scatter_kernel<<<NB_EDGE, 256, 0, stream>>>(ei32, flag, rowstart, cursor, a_s, a_d, rec);

    dim3 g1((NN + 127) / 128, HC / 128);
    gemm_mfma<false, true><<<g1, 256, 0, stream>>>(xb, Wb, nullptr, hb, NN, HC, FIN);

    agg6_kernel<<<NN / 4, 256, 0, stream>>>(hb, rowstart, rec, bias, aggb);

    dim3 g2((NN + 127) / 128, CCOUT / 128);
    gemm_mfma<true, false><<<g2, 256, 0, stream>>>(aggb, linwb, lin_b, out, NN, CCOUT, HC);
}

// Round 9
// 276.557 us; speedup vs baseline: 1.0892x; 1.0892x over previous
//
#include <hip/hip_runtime.h>
#include <hip/hip_fp16.h>
#include <math.h>

#define NN 50000
#define EE 800000
#define ET (EE + NN)
#define FIN 256
#define CCOUT 128
#define HH 2
#define HC 256
#define NEG 0.2f

#define NB_EDGE ((ET + 255) / 256)      // 3321
#define NB_SCAN ((NN + 255) / 256)
#define NB_XPREP (NN / 4)

// prep grid: 1 detect + 2 watt + 64 W-conv + 32 linw-conv
#define PREP_W_BLOCKS 64
#define PREP_LW_BLOCKS 32
#define PREP_GRID (3 + PREP_W_BLOCKS + PREP_LW_BLOCKS)

// fused scatter+gemm1 interleave: groups of 5 blocks = 4 scatter + 1 gemm
#define G1X 391                          // (NN+127)/128
#define G1Y 2                            // HC/128
#define NB_G1 (G1X * G1Y)                // 782
#define FUSE_HEAD (NB_G1 * 5)            // 3910 (covers 3128 scatter + 782 gemm)
#define SCAT_IN_HEAD (NB_G1 * 4)         // 3128
#define NB_FUSE (NB_EDGE + NB_G1)        // 4103

typedef __attribute__((ext_vector_type(8))) short short8;
typedef __attribute__((ext_vector_type(4))) float floatx4;

// ---------------- bf16 helpers ----------------
__device__ __forceinline__ unsigned short f2bf(float f)
{
    union { float f; unsigned int u; } x; x.f = f;
    unsigned int r = x.u + 0x7fffu + ((x.u >> 16) & 1u);   // RNE
    return (unsigned short)(r >> 16);
}
__device__ __forceinline__ float bf_lo(unsigned int u)
{
    union { unsigned int u; float f; } x; x.u = u << 16;
    return x.f;
}
__device__ __forceinline__ float bf_hi(unsigned int u)
{
    union { unsigned int u; float f; } x; x.u = u & 0xffff0000u;
    return x.f;
}
__device__ __forceinline__ float h2f_bits(unsigned short u)
{
    __half h = *(const __half*)&u;
    return __half2float(h);
}

__device__ __forceinline__ int load_idx(const int* ei32, int is64, int pos)
{
    return is64 ? ei32[2 * pos] : ei32[pos];
}

// ---------------- fused prep: detect + watt + weight bf16 conversion ----------------
__global__ __launch_bounds__(256) void prep_kernel(const float* __restrict__ W,
                                                   const float* __restrict__ att_s,
                                                   const float* __restrict__ att_d,
                                                   const float* __restrict__ lin_w,
                                                   const int* __restrict__ ei32,
                                                   float* __restrict__ was,
                                                   float* __restrict__ wad,
                                                   unsigned short* __restrict__ Wb,
                                                   unsigned short* __restrict__ linwb,
                                                   int* __restrict__ flag)
{
    int b = blockIdx.x, t = threadIdx.x;
    if (b == 0) {
        if (t < 64) {
            int v = ei32[2 * t + 1];
            unsigned long long m = __ballot(v != 0);
            if (t == 0) *flag = (m == 0ull) ? 1 : 0;
        }
    } else if (b <= 2) {
        int hd = b - 1;
        float as = 0.f, ad = 0.f;
        for (int c = 0; c < CCOUT; c++) {
            float wv = W[(size_t)(hd * CCOUT + c) * FIN + t];
            as += att_s[hd * CCOUT + c] * wv;
            ad += att_d[hd * CCOUT + c] * wv;
        }
        was[hd * FIN + t] = as;
        wad[hd * FIN + t] = ad;
    } else if (b < 3 + PREP_W_BLOCKS) {
        int i = (b - 3) * 256 + t;
        float4 v = *(const float4*)(W + (size_t)i * 4);
        ushort4 o;
        o.x = f2bf(v.x); o.y = f2bf(v.y); o.z = f2bf(v.z); o.w = f2bf(v.w);
        *(ushort4*)(Wb + (size_t)i * 4) = o;
    } else {
        int i = (b - 3 - PREP_W_BLOCKS) * 256 + t;
        float4 v = *(const float4*)(lin_w + (size_t)i * 4);
        ushort4 o;
        o.x = f2bf(v.x); o.y = f2bf(v.y); o.z = f2bf(v.z); o.w = f2bf(v.w);
        *(ushort4*)(linwb + (size_t)i * 4) = o;
    }
}

// ---------------- fused: x->bf16 + fp32 attention logits || degree count + eord ----------------
// (R7 scheme: the atomic-with-return lives here; scatter is atomic-free.)
__global__ __launch_bounds__(256) void xprep_count_kernel(const float* __restrict__ x,
                                                          const float* __restrict__ was,
                                                          const float* __restrict__ wad,
                                                          unsigned short* __restrict__ xb,
                                                          float* __restrict__ a_s,
                                                          float* __restrict__ a_d,
                                                          const int* __restrict__ ei32,
                                                          const int* __restrict__ flag,
                                                          int* __restrict__ deg,
                                                          int* __restrict__ eord)
{
    int b = blockIdx.x, t = threadIdx.x;
    if (b < NB_XPREP) {
        int w = t >> 6, l = t & 63;
        int n = b * 4 + w;
        float4 xv = *(const float4*)(x + (size_t)n * FIN + l * 4);
        ushort4 xs;
        xs.x = f2bf(xv.x); xs.y = f2bf(xv.y); xs.z = f2bf(xv.z); xs.w = f2bf(xv.w);
        *(ushort4*)(xb + (size_t)n * FIN + l * 4) = xs;

        float4 s0 = *(const float4*)(was + l * 4);
        float4 s1 = *(const float4*)(was + FIN + l * 4);
        float4 d0 = *(const float4*)(wad + l * 4);
        float4 d1 = *(const float4*)(wad + FIN + l * 4);
        float vs0 = xv.x * s0.x + xv.y * s0.y + xv.z * s0.z + xv.w * s0.w;
        float vs1 = xv.x * s1.x + xv.y * s1.y + xv.z * s1.z + xv.w * s1.w;
        float vd0 = xv.x * d0.x + xv.y * d0.y + xv.z * d0.z + xv.w * d0.w;
        float vd1 = xv.x * d1.x + xv.y * d1.y + xv.z * d1.z + xv.w * d1.w;
#pragma unroll
        for (int off = 32; off > 0; off >>= 1) {
            vs0 += __shfl_down(vs0, off);
            vs1 += __shfl_down(vs1, off);
            vd0 += __shfl_down(vd0, off);
            vd1 += __shfl_down(vd1, off);
        }
        if (l == 0) {
            a_s[n * 2 + 0] = vs0; a_s[n * 2 + 1] = vs1;
            a_d[n * 2 + 0] = vd0; a_d[n * 2 + 1] = vd1;
        }
    } else {
        int e = (b - NB_XPREP) * 256 + t;
        if (e < ET) {
            int is64 = *flag;
            int d = (e < EE) ? load_idx(ei32, is64, EE + e) : (e - EE);
            eord[e] = atomicAdd(&deg[d], 1);
        }
    }
}

// ---------------- MFMA bf16 GEMM (standalone, used for GEMM2) ----------------
template <bool ADD_BIAS, bool OUT_BF16>
__global__ __launch_bounds__(256) void gemm_mfma(const unsigned short* __restrict__ A,
                                                 const unsigned short* __restrict__ B,
                                                 const float* __restrict__ bias,
                                                 void* __restrict__ Cout,
                                                 int M, int N, int K)
{
    const int LDT = 40;
    __shared__ unsigned short As[128 * LDT];
    __shared__ unsigned short Bs[128 * LDT];

    int tid = threadIdx.x;
    int wave = tid >> 6, lane = tid & 63;
    int wr = wave >> 1, wc = wave & 1;
    int quad = lane >> 4, l16 = lane & 15;
    int bm0 = blockIdx.x * 128;
    int bn0 = blockIdx.y * 128;

    floatx4 acc[4][4] = {};

    for (int kk = 0; kk < K; kk += 32) {
#pragma unroll
        for (int p = 0; p < 2; p++) {
            int idx = p * 256 + tid;
            int row = idx >> 2, seg = idx & 3;
            int grow = bm0 + row; if (grow >= M) grow = M - 1;
            uint4 va = *(const uint4*)(A + (size_t)grow * K + kk + seg * 8);
            *(uint4*)(&As[row * LDT + seg * 8]) = va;
            uint4 vb = *(const uint4*)(B + (size_t)(bn0 + row) * K + kk + seg * 8);
            *(uint4*)(&Bs[row * LDT + seg * 8]) = vb;
        }
        __syncthreads();

        short8 af[4], bfr[4];
#pragma unroll
        for (int mi = 0; mi < 4; mi++)
            af[mi] = *(const short8*)(&As[(wr * 64 + mi * 16 + l16) * LDT + quad * 8]);
#pragma unroll
        for (int ni = 0; ni < 4; ni++)
            bfr[ni] = *(const short8*)(&Bs[(wc * 64 + ni * 16 + l16) * LDT + quad * 8]);
#pragma unroll
        for (int mi = 0; mi < 4; mi++)
#pragma unroll
            for (int ni = 0; ni < 4; ni++)
                acc[mi][ni] = __builtin_amdgcn_mfma_f32_16x16x32_bf16(af[mi], bfr[ni], acc[mi][ni], 0, 0, 0);
        __syncthreads();
    }

#pragma unroll
    for (int mi = 0; mi < 4; mi++) {
#pragma unroll
        for (int ni = 0; ni < 4; ni++) {
            int col = bn0 + wc * 64 + ni * 16 + l16;
#pragma unroll
            for (int r = 0; r < 4; r++) {
                int row = bm0 + wr * 64 + mi * 16 + quad * 4 + r;
                if (row < M) {
                    float v = acc[mi][ni][r];
                    if (ADD_BIAS) v += bias[col];
                    if (OUT_BF16)
                        ((unsigned short*)Cout)[(size_t)row * N + col] = f2bf(v);
                    else
                        ((float*)Cout)[(size_t)row * N + col] = v;
                }
            }
        }
    }
}

// ---------------- FUSED: scatter (latency-bound) + GEMM1 (MFMA-bound), interleaved 4:1 ----
// Independent work co-resident on each CU: scatter waves wait on VMEM while gemm
// waves issue MFMA (m114: co-scheduling ≈ max, not sum).
__global__ __launch_bounds__(256) void scatter_gemm1_kernel(
        const int* __restrict__ ei32, const int* __restrict__ flag,
        const int* __restrict__ eord, const int* __restrict__ rowstart,
        const float* __restrict__ a_s, const float* __restrict__ a_d,
        uint2* __restrict__ rec,
        const unsigned short* __restrict__ A,   // xb [NN, FIN]
        const unsigned short* __restrict__ B,   // Wb [HC, FIN]
        unsigned short* __restrict__ hb)        // out [NN, HC]
{
    const int LDT = 40;
    __shared__ unsigned short As[128 * LDT];
    __shared__ unsigned short Bs[128 * LDT];

    int b = blockIdx.x, tid = threadIdx.x;
    int sb = -1, gb = -1;
    if (b < FUSE_HEAD) {
        int g = b / 5, r = b - g * 5;
        if (r < 4) sb = g * 4 + r; else gb = g;
    } else {
        sb = SCAT_IN_HEAD + (b - FUSE_HEAD);
    }

    if (sb >= 0) {
        // ---- scatter path (atomic-free; slot = rowstart[d] + eord[e]) ----
        int e = sb * 256 + tid;
        if (e < ET) {
            int is64 = *flag;
            int s, d;
            if (e < EE) { s = load_idx(ei32, is64, e); d = load_idx(ei32, is64, EE + e); }
            else { s = d = e - EE; }
            float e0 = a_s[s * 2 + 0] + a_d[d * 2 + 0];
            float e1 = a_s[s * 2 + 1] + a_d[d * 2 + 1];
            e0 = e0 > 0.f ? e0 : NEG * e0;
            e1 = e1 > 0.f ? e1 : NEG * e1;
            __half2 hp = __floats2half2_rn(__expf(e0), __expf(e1));
            uint2 r;
            r.x = (unsigned int)s;
            r.y = *(unsigned int*)&hp;
            rec[rowstart[d] + eord[e]] = r;
        }
        return;
    }

    // ---- gemm1 path: hb[NN,HC] = xb @ Wb^T, output bf16, no bias ----
    int bx = gb % G1X, by = gb / G1X;
    int wave = tid >> 6, lane = tid & 63;
    int wr = wave >> 1, wc = wave & 1;
    int quad = lane >> 4, l16 = lane & 15;
    int bm0 = bx * 128;
    int bn0 = by * 128;

    floatx4 acc[4][4] = {};

    for (int kk = 0; kk < FIN; kk += 32) {
#pragma unroll
        for (int p = 0; p < 2; p++) {
            int idx = p * 256 + tid;
            int row = idx >> 2, seg = idx & 3;
            int grow = bm0 + row; if (grow >= NN) grow = NN - 1;
            uint4 va = *(const uint4*)(A + (size_t)grow * FIN + kk + seg * 8);
            *(uint4*)(&As[row * LDT + seg * 8]) = va;
            uint4 vb = *(const uint4*)(B + (size_t)(bn0 + row) * FIN + kk + seg * 8);
            *(uint4*)(&Bs[row * LDT + seg * 8]) = vb;
        }
        __syncthreads();

        short8 af[4], bfr[4];
#pragma unroll
        for (int mi = 0; mi < 4; mi++)
            af[mi] = *(const short8*)(&As[(wr * 64 + mi * 16 + l16) * LDT + quad * 8]);
#pragma unroll
        for (int ni = 0; ni < 4; ni++)
            bfr[ni] = *(const short8*)(&Bs[(wc * 64 + ni * 16 + l16) * LDT + quad * 8]);
#pragma unroll
        for (int mi = 0; mi < 4; mi++)
#pragma unroll
            for (int ni = 0; ni < 4; ni++)
                acc[mi][ni] = __builtin_amdgcn_mfma_f32_16x16x32_bf16(af[mi], bfr[ni], acc[mi][ni], 0, 0, 0);
        __syncthreads();
    }

#pragma unroll
    for (int mi = 0; mi < 4; mi++) {
#pragma unroll
        for (int ni = 0; ni < 4; ni++) {
            int col = bn0 + wc * 64 + ni * 16 + l16;
#pragma unroll
            for (int r = 0; r < 4; r++) {
                int row = bm0 + wr * 64 + mi * 16 + quad * 4 + r;
                if (row < NN)
                    hb[(size_t)row * HC + col] = f2bf(acc[mi][ni][r]);
            }
        }
    }
}

// ---------------- scan1: per-block inclusive scan + block totals ----------------
__global__ __launch_bounds__(256) void scan1(const int* __restrict__ deg,
                                             int* __restrict__ tmp, int* __restrict__ bsum)
{
    __shared__ int s[256];
    int i = blockIdx.x * 256 + threadIdx.x;
    int v = (i < NN) ? deg[i] : 0;
    s[threadIdx.x] = v;
    __syncthreads();
    for (int off = 1; off < 256; off <<= 1) {
        int add = (threadIdx.x >= off) ? s[threadIdx.x - off] : 0;
        __syncthreads();
        s[threadIdx.x] += add;
        __syncthreads();
    }
    if (i < NN) tmp[i] = s[threadIdx.x];
    if (threadIdx.x == 255) bsum[blockIdx.x] = s[255];
}

// ---------------- scan2+scan3 fused ----------------
__global__ __launch_bounds__(256) void scan23(const int* __restrict__ deg,
                                              const int* __restrict__ tmp,
                                              const int* __restrict__ bsum,
                                              int* __restrict__ rowstart)
{
    __shared__ int s[256];
    int b = blockIdx.x, t = threadIdx.x;
    int v = (t < NB_SCAN && t < b) ? bsum[t] : 0;
    s[t] = v;
    __syncthreads();
#pragma unroll
    for (int off = 128; off > 0; off >>= 1) {
        if (t < off) s[t] += s[t + off];
        __syncthreads();
    }
    int offset = s[0];
    int i = b * 256 + t;
    if (i < NN) rowstart[i] = tmp[i] - deg[i] + offset;
    if (i == 0) rowstart[NN] = ET;
}

// ---------------- gather-aggregate: wave-per-node, half-wave edges, 16B loads ----------------
// NOTE: no dynamic register indexing (R5: compiler spills via LDS scratch).
__global__ __launch_bounds__(256) void agg6_kernel(const unsigned short* __restrict__ hb,
                                                   const int* __restrict__ rowstart,
                                                   const uint2* __restrict__ rec,
                                                   const float* __restrict__ bias,
                                                   unsigned short* __restrict__ aggb)
{
    int wave = threadIdx.x >> 6, lane = threadIdx.x & 63;
    int d = blockIdx.x * 4 + wave;
    int half = lane >> 5;
    int l = lane & 31;
    int hshift = (l >> 4) << 4;
    int c = l * 8;
    int j0 = rowstart[d], j1 = rowstart[d + 1];

    float a0 = 0.f, a1 = 0.f, a2 = 0.f, a3 = 0.f;
    float a4 = 0.f, a5 = 0.f, a6 = 0.f, a7 = 0.f;
    float psum = 0.f;

    int j = j0 + half;
    for (; j + 2 < j1; j += 4) {
        uint2 r0 = rec[j], r1 = rec[j + 2];
        float p0 = h2f_bits((unsigned short)(r0.y >> hshift));
        float p1 = h2f_bits((unsigned short)(r1.y >> hshift));
        psum += p0 + p1;
        uint4 h0 = *(const uint4*)(hb + (size_t)r0.x * HC + c);
        uint4 h1 = *(const uint4*)(hb + (size_t)r1.x * HC + c);
        a0 += p0 * bf_lo(h0.x) + p1 * bf_lo(h1.x);
        a1 += p0 * bf_hi(h0.x) + p1 * bf_hi(h1.x);
        a2 += p0 * bf_lo(h0.y) + p1 * bf_lo(h1.y);
        a3 += p0 * bf_hi(h0.y) + p1 * bf_hi(h1.y);
        a4 += p0 * bf_lo(h0.z) + p1 * bf_lo(h1.z);
        a5 += p0 * bf_hi(h0.z) + p1 * bf_hi(h1.z);
        a6 += p0 * bf_lo(h0.w) + p1 * bf_lo(h1.w);
        a7 += p0 * bf_hi(h0.w) + p1 * bf_hi(h1.w);
    }
    for (; j < j1; j += 2) {
        uint2 r0 = rec[j];
        float p0 = h2f_bits((unsigned short)(r0.y >> hshift));
        psum += p0;
        uint4 h0 = *(const uint4*)(hb + (size_t)r0.x * HC + c);
        a0 += p0 * bf_lo(h0.x);
        a1 += p0 * bf_hi(h0.x);
        a2 += p0 * bf_lo(h0.y);
        a3 += p0 * bf_hi(h0.y);
        a4 += p0 * bf_lo(h0.z);
        a5 += p0 * bf_hi(h0.z);
        a6 += p0 * bf_lo(h0.w);
        a7 += p0 * bf_hi(h0.w);
    }

    a0 += __shfl_xor(a0, 32);
    a1 += __shfl_xor(a1, 32);
    a2 += __shfl_xor(a2, 32);
    a3 += __shfl_xor(a3, 32);
    a4 += __shfl_xor(a4, 32);
    a5 += __shfl_xor(a5, 32);
    a6 += __shfl_xor(a6, 32);
    a7 += __shfl_xor(a7, 32);
    psum += __shfl_xor(psum, 32);

    if (half == 0) {
        float inv = 1.f / fmaxf(psum, 1e-16f);
        float4 b0 = *(const float4*)(bias + c);
        float4 b1 = *(const float4*)(bias + c + 4);
        float v0 = a0 * inv + b0.x;
        float v1 = a1 * inv + b0.y;
        float v2 = a2 * inv + b0.z;
        float v3 = a3 * inv + b0.w;
        float v4 = a4 * inv + b1.x;
        float v5 = a5 * inv + b1.y;
        float v6 = a6 * inv + b1.z;
        float v7 = a7 * inv + b1.w;
        v0 = v0 > 0.f ? v0 : expm1f(v0);
        v1 = v1 > 0.f ? v1 : expm1f(v1);
        v2 = v2 > 0.f ? v2 : expm1f(v2);
        v3 = v3 > 0.f ? v3 : expm1f(v3);
        v4 = v4 > 0.f ? v4 : expm1f(v4);
        v5 = v5 > 0.f ? v5 : expm1f(v5);
        v6 = v6 > 0.f ? v6 : expm1f(v6);
        v7 = v7 > 0.f ? v7 : expm1f(v7);
        uint4 o;
        o.x = (unsigned int)f2bf(v0) | ((unsigned int)f2bf(v1) << 16);
        o.y = (unsigned int)f2bf(v2) | ((unsigned int)f2bf(v3) << 16);
        o.z = (unsigned int)f2bf(v4) | ((unsigned int)f2bf(v5) << 16);
        o.w = (unsigned int)f2bf(v6) | ((unsigned int)f2bf(v7) << 16);
        *(uint4*)(aggb + (size_t)d * HC + c) = o;
    }
}

// ---------------- launch ----------------
extern "C" void kernel_launch(void* const* d_in, const int* in_sizes, int n_in,
                              void* d_out, int out_size, void* d_ws, size_t ws_size,
                              hipStream_t stream)
{
    const float* x       = (const float*)d_in[0];
    const int*   ei32    = (const int*)d_in[1];
    const float* W       = (const float*)d_in[2];
    const float* att_src = (const float*)d_in[3];
    const float* att_dst = (const float*)d_in[4];
    const float* bias    = (const float*)d_in[5];
    const float* lin_w   = (const float*)d_in[6];
    const float* lin_b   = (const float*)d_in[7];
    float* out = (float*)d_out;

    char* ws = (char*)d_ws;
    size_t off = 0;
    auto alloc = [&](size_t bytes) -> void* {
        void* p = ws + off;
        off += (bytes + 255) & ~(size_t)255;
        return p;
    };

    // zero-init region first (deg only)
    int*   deg    = (int*)alloc((size_t)NN * 4);
    size_t zero_bytes = off;

    int*   flag     = (int*)alloc(256);
    int*   tmp      = (int*)alloc((size_t)NN * 4);
    int*   bsum     = (int*)alloc(1024);
    int*   rowstart = (int*)alloc((size_t)(NN + 1) * 4);
    int*   eord     = (int*)alloc((size_t)ET * 4);
    float* was      = (float*)alloc((size_t)HH * FIN * 4);
    float* wad      = (float*)alloc((size_t)HH * FIN * 4);
    float* a_s      = (float*)alloc((size_t)NN * 2 * 4);
    float* a_d      = (float*)alloc((size_t)NN * 2 * 4);
    uint2* rec      = (uint2*)alloc((size_t)ET * 8);
    unsigned short* xb     = (unsigned short*)alloc((size_t)NN * FIN * 2);
    unsigned short* Wb     = (unsigned short*)alloc((size_t)HC * FIN * 2);
    unsigned short* linwb  = (unsigned short*)alloc((size_t)CCOUT * HC * 2);
    unsigned short* hb     = (unsigned short*)alloc((size_t)NN * HC * 2);
    unsigned short* aggb   = (unsigned short*)alloc((size_t)NN * HC * 2);

    hipMemsetAsync(d_ws, 0, zero_bytes, stream);

    prep_kernel<<<PREP_GRID, 256, 0, stream>>>(W, att_src, att_dst, lin_w, ei32,
                                               was, wad, Wb, linwb, flag);

    xprep_count_kernel<<<NB_XPREP + NB_EDGE, 256, 0, stream>>>(x, was, wad, xb, a_s, a_d,
                                                               ei32, flag, deg, eord);

    scan1<<<NB_SCAN, 256, 0, stream>>>(deg, tmp, bsum);
    scan23<<<NB_SCAN, 256, 0, stream>>>(deg, tmp, bsum, rowstart);

    scatter_gemm1_kernel<<<NB_FUSE, 256, 0, stream>>>(ei32, flag, eord, rowstart,
                                                      a_s, a_d, rec, xb, Wb, hb);

    agg6_kernel<<<NN / 4, 256, 0, stream>>>(hb, rowstart, rec, bias, aggb);

    dim3 g2((NN + 127) / 128, CCOUT / 128);
    gemm_mfma<true, false><<<g2, 256, 0, stream>>>(aggb, linwb, lin_b, out, NN, CCOUT, HC);
}

// Round 10
// 273.420 us; speedup vs baseline: 1.1017x; 1.0115x over previous
//
#include <hip/hip_runtime.h>
#include <hip/hip_fp16.h>
#include <math.h>

#define NN 50000
#define EE 800000
#define ET (EE + NN)
#define FIN 256
#define CCOUT 128
#define HH 2
#define HC 256
#define NEG 0.2f

#define NB_EDGE ((ET + 255) / 256)      // 3321
#define NB_EDGE4 ((ET + 1023) / 1024)   // 831 (count: 4 edges/thread)
#define NB_SCAN ((NN + 255) / 256)
#define NB_XPREP (NN / 4)

// prep grid: 1 detect + 2 watt + 64 W-conv + 32 linw-conv
#define PREP_W_BLOCKS 64
#define PREP_LW_BLOCKS 32
#define PREP_GRID (3 + PREP_W_BLOCKS + PREP_LW_BLOCKS)

// fused scatter+gemm1 interleave: groups of 5 blocks = 4 scatter + 1 gemm
#define G1X 391                          // (NN+127)/128
#define G1Y 2                            // HC/128
#define NB_G1 (G1X * G1Y)                // 782
#define FUSE_HEAD (NB_G1 * 5)            // 3910
#define SCAT_IN_HEAD (NB_G1 * 4)         // 3128
#define NB_FUSE (NB_EDGE + NB_G1)        // 4103

typedef __attribute__((ext_vector_type(8))) short short8;
typedef __attribute__((ext_vector_type(4))) float floatx4;

// ---------------- bf16 helpers ----------------
__device__ __forceinline__ unsigned short f2bf(float f)
{
    union { float f; unsigned int u; } x; x.f = f;
    unsigned int r = x.u + 0x7fffu + ((x.u >> 16) & 1u);   // RNE
    return (unsigned short)(r >> 16);
}
__device__ __forceinline__ float bf_lo(unsigned int u)
{
    union { unsigned int u; float f; } x; x.u = u << 16;
    return x.f;
}
__device__ __forceinline__ float bf_hi(unsigned int u)
{
    union { unsigned int u; float f; } x; x.u = u & 0xffff0000u;
    return x.f;
}
__device__ __forceinline__ float h2f_bits(unsigned short u)
{
    __half h = *(const __half*)&u;
    return __half2float(h);
}

__device__ __forceinline__ int load_idx(const int* ei32, int is64, int pos)
{
    return is64 ? ei32[2 * pos] : ei32[pos];
}

// ---------------- fused prep: detect + watt + weight bf16 conversion ----------------
__global__ __launch_bounds__(256) void prep_kernel(const float* __restrict__ W,
                                                   const float* __restrict__ att_s,
                                                   const float* __restrict__ att_d,
                                                   const float* __restrict__ lin_w,
                                                   const int* __restrict__ ei32,
                                                   float* __restrict__ was,
                                                   float* __restrict__ wad,
                                                   unsigned short* __restrict__ Wb,
                                                   unsigned short* __restrict__ linwb,
                                                   int* __restrict__ flag)
{
    int b = blockIdx.x, t = threadIdx.x;
    if (b == 0) {
        if (t < 64) {
            int v = ei32[2 * t + 1];
            unsigned long long m = __ballot(v != 0);
            if (t == 0) *flag = (m == 0ull) ? 1 : 0;
        }
    } else if (b <= 2) {
        int hd = b - 1;
        float as = 0.f, ad = 0.f;
        for (int c = 0; c < CCOUT; c++) {
            float wv = W[(size_t)(hd * CCOUT + c) * FIN + t];
            as += att_s[hd * CCOUT + c] * wv;
            ad += att_d[hd * CCOUT + c] * wv;
        }
        was[hd * FIN + t] = as;
        wad[hd * FIN + t] = ad;
    } else if (b < 3 + PREP_W_BLOCKS) {
        int i = (b - 3) * 256 + t;
        float4 v = *(const float4*)(W + (size_t)i * 4);
        ushort4 o;
        o.x = f2bf(v.x); o.y = f2bf(v.y); o.z = f2bf(v.z); o.w = f2bf(v.w);
        *(ushort4*)(Wb + (size_t)i * 4) = o;
    } else {
        int i = (b - 3 - PREP_W_BLOCKS) * 256 + t;
        float4 v = *(const float4*)(lin_w + (size_t)i * 4);
        ushort4 o;
        o.x = f2bf(v.x); o.y = f2bf(v.y); o.z = f2bf(v.z); o.w = f2bf(v.w);
        *(ushort4*)(linwb + (size_t)i * 4) = o;
    }
}

// ---------------- fused: x->bf16 + fp32 attention logits || count (4 edges/thread) ----------------
// count half: 4 independent atomicAdd-with-return in flight per thread (MLP test:
// if latency-bound this is ~4x faster; if coherence-point-throughput-bound, unchanged).
__global__ __launch_bounds__(256) void xprep_count_kernel(const float* __restrict__ x,
                                                          const float* __restrict__ was,
                                                          const float* __restrict__ wad,
                                                          unsigned short* __restrict__ xb,
                                                          float* __restrict__ a_s,
                                                          float* __restrict__ a_d,
                                                          const int* __restrict__ ei32,
                                                          const int* __restrict__ flag,
                                                          int* __restrict__ deg,
                                                          int* __restrict__ eord)
{
    int b = blockIdx.x, t = threadIdx.x;
    if (b < NB_XPREP) {
        int w = t >> 6, l = t & 63;
        int n = b * 4 + w;
        float4 xv = *(const float4*)(x + (size_t)n * FIN + l * 4);
        ushort4 xs;
        xs.x = f2bf(xv.x); xs.y = f2bf(xv.y); xs.z = f2bf(xv.z); xs.w = f2bf(xv.w);
        *(ushort4*)(xb + (size_t)n * FIN + l * 4) = xs;

        float4 s0 = *(const float4*)(was + l * 4);
        float4 s1 = *(const float4*)(was + FIN + l * 4);
        float4 d0 = *(const float4*)(wad + l * 4);
        float4 d1 = *(const float4*)(wad + FIN + l * 4);
        float vs0 = xv.x * s0.x + xv.y * s0.y + xv.z * s0.z + xv.w * s0.w;
        float vs1 = xv.x * s1.x + xv.y * s1.y + xv.z * s1.z + xv.w * s1.w;
        float vd0 = xv.x * d0.x + xv.y * d0.y + xv.z * d0.z + xv.w * d0.w;
        float vd1 = xv.x * d1.x + xv.y * d1.y + xv.z * d1.z + xv.w * d1.w;
#pragma unroll
        for (int off = 32; off > 0; off >>= 1) {
            vs0 += __shfl_down(vs0, off);
            vs1 += __shfl_down(vs1, off);
            vd0 += __shfl_down(vd0, off);
            vd1 += __shfl_down(vd1, off);
        }
        if (l == 0) {
            a_s[n * 2 + 0] = vs0; a_s[n * 2 + 1] = vs1;
            a_d[n * 2 + 0] = vd0; a_d[n * 2 + 1] = vd1;
        }
    } else {
        int base = (b - NB_XPREP) * 1024 + t;
        int is64 = *flag;
        int e0 = base, e1 = base + 256, e2 = base + 512, e3 = base + 768;
        int d0 = -1, d1 = -1, d2 = -1, d3 = -1;
        if (e0 < ET) d0 = (e0 < EE) ? load_idx(ei32, is64, EE + e0) : (e0 - EE);
        if (e1 < ET) d1 = (e1 < EE) ? load_idx(ei32, is64, EE + e1) : (e1 - EE);
        if (e2 < ET) d2 = (e2 < EE) ? load_idx(ei32, is64, EE + e2) : (e2 - EE);
        if (e3 < ET) d3 = (e3 < EE) ? load_idx(ei32, is64, EE + e3) : (e3 - EE);
        int r0 = 0, r1 = 0, r2 = 0, r3 = 0;
        if (d0 >= 0) r0 = atomicAdd(&deg[d0], 1);
        if (d1 >= 0) r1 = atomicAdd(&deg[d1], 1);
        if (d2 >= 0) r2 = atomicAdd(&deg[d2], 1);
        if (d3 >= 0) r3 = atomicAdd(&deg[d3], 1);
        if (d0 >= 0) eord[e0] = r0;
        if (d1 >= 0) eord[e1] = r1;
        if (d2 >= 0) eord[e2] = r2;
        if (d3 >= 0) eord[e3] = r3;
    }
}

// ---------------- MFMA bf16 GEMM (standalone, used for GEMM2) ----------------
template <bool ADD_BIAS, bool OUT_BF16>
__global__ __launch_bounds__(256) void gemm_mfma(const unsigned short* __restrict__ A,
                                                 const unsigned short* __restrict__ B,
                                                 const float* __restrict__ bias,
                                                 void* __restrict__ Cout,
                                                 int M, int N, int K)
{
    const int LDT = 40;
    __shared__ unsigned short As[128 * LDT];
    __shared__ unsigned short Bs[128 * LDT];

    int tid = threadIdx.x;
    int wave = tid >> 6, lane = tid & 63;
    int wr = wave >> 1, wc = wave & 1;
    int quad = lane >> 4, l16 = lane & 15;
    int bm0 = blockIdx.x * 128;
    int bn0 = blockIdx.y * 128;

    floatx4 acc[4][4] = {};

    for (int kk = 0; kk < K; kk += 32) {
#pragma unroll
        for (int p = 0; p < 2; p++) {
            int idx = p * 256 + tid;
            int row = idx >> 2, seg = idx & 3;
            int grow = bm0 + row; if (grow >= M) grow = M - 1;
            uint4 va = *(const uint4*)(A + (size_t)grow * K + kk + seg * 8);
            *(uint4*)(&As[row * LDT + seg * 8]) = va;
            uint4 vb = *(const uint4*)(B + (size_t)(bn0 + row) * K + kk + seg * 8);
            *(uint4*)(&Bs[row * LDT + seg * 8]) = vb;
        }
        __syncthreads();

        short8 af[4], bfr[4];
#pragma unroll
        for (int mi = 0; mi < 4; mi++)
            af[mi] = *(const short8*)(&As[(wr * 64 + mi * 16 + l16) * LDT + quad * 8]);
#pragma unroll
        for (int ni = 0; ni < 4; ni++)
            bfr[ni] = *(const short8*)(&Bs[(wc * 64 + ni * 16 + l16) * LDT + quad * 8]);
#pragma unroll
        for (int mi = 0; mi < 4; mi++)
#pragma unroll
            for (int ni = 0; ni < 4; ni++)
                acc[mi][ni] = __builtin_amdgcn_mfma_f32_16x16x32_bf16(af[mi], bfr[ni], acc[mi][ni], 0, 0, 0);
        __syncthreads();
    }

#pragma unroll
    for (int mi = 0; mi < 4; mi++) {
#pragma unroll
        for (int ni = 0; ni < 4; ni++) {
            int col = bn0 + wc * 64 + ni * 16 + l16;
#pragma unroll
            for (int r = 0; r < 4; r++) {
                int row = bm0 + wr * 64 + mi * 16 + quad * 4 + r;
                if (row < M) {
                    float v = acc[mi][ni][r];
                    if (ADD_BIAS) v += bias[col];
                    if (OUT_BF16)
                        ((unsigned short*)Cout)[(size_t)row * N + col] = f2bf(v);
                    else
                        ((float*)Cout)[(size_t)row * N + col] = v;
                }
            }
        }
    }
}

// ---------------- FUSED: scatter (latency-bound) + GEMM1 (MFMA-bound), interleaved 4:1 ----
__global__ __launch_bounds__(256) void scatter_gemm1_kernel(
        const int* __restrict__ ei32, const int* __restrict__ flag,
        const int* __restrict__ eord, const int* __restrict__ rowstart,
        const float* __restrict__ a_s, const float* __restrict__ a_d,
        uint2* __restrict__ rec,
        const unsigned short* __restrict__ A,   // xb [NN, FIN]
        const unsigned short* __restrict__ B,   // Wb [HC, FIN]
        unsigned short* __restrict__ hb)        // out [NN, HC]
{
    const int LDT = 40;
    __shared__ unsigned short As[128 * LDT];
    __shared__ unsigned short Bs[128 * LDT];

    int b = blockIdx.x, tid = threadIdx.x;
    int sb = -1, gb = -1;
    if (b < FUSE_HEAD) {
        int g = b / 5, r = b - g * 5;
        if (r < 4) sb = g * 4 + r; else gb = g;
    } else {
        sb = SCAT_IN_HEAD + (b - FUSE_HEAD);
    }

    if (sb >= 0) {
        int e = sb * 256 + tid;
        if (e < ET) {
            int is64 = *flag;
            int s, d;
            if (e < EE) { s = load_idx(ei32, is64, e); d = load_idx(ei32, is64, EE + e); }
            else { s = d = e - EE; }
            float e0 = a_s[s * 2 + 0] + a_d[d * 2 + 0];
            float e1 = a_s[s * 2 + 1] + a_d[d * 2 + 1];
            e0 = e0 > 0.f ? e0 : NEG * e0;
            e1 = e1 > 0.f ? e1 : NEG * e1;
            __half2 hp = __floats2half2_rn(__expf(e0), __expf(e1));
            uint2 r;
            r.x = (unsigned int)s;
            r.y = *(unsigned int*)&hp;
            rec[rowstart[d] + eord[e]] = r;
        }
        return;
    }

    int bx = gb % G1X, by = gb / G1X;
    int wave = tid >> 6, lane = tid & 63;
    int wr = wave >> 1, wc = wave & 1;
    int quad = lane >> 4, l16 = lane & 15;
    int bm0 = bx * 128;
    int bn0 = by * 128;

    floatx4 acc[4][4] = {};

    for (int kk = 0; kk < FIN; kk += 32) {
#pragma unroll
        for (int p = 0; p < 2; p++) {
            int idx = p * 256 + tid;
            int row = idx >> 2, seg = idx & 3;
            int grow = bm0 + row; if (grow >= NN) grow = NN - 1;
            uint4 va = *(const uint4*)(A + (size_t)grow * FIN + kk + seg * 8);
            *(uint4*)(&As[row * LDT + seg * 8]) = va;
            uint4 vb = *(const uint4*)(B + (size_t)(bn0 + row) * FIN + kk + seg * 8);
            *(uint4*)(&Bs[row * LDT + seg * 8]) = vb;
        }
        __syncthreads();

        short8 af[4], bfr[4];
#pragma unroll
        for (int mi = 0; mi < 4; mi++)
            af[mi] = *(const short8*)(&As[(wr * 64 + mi * 16 + l16) * LDT + quad * 8]);
#pragma unroll
        for (int ni = 0; ni < 4; ni++)
            bfr[ni] = *(const short8*)(&Bs[(wc * 64 + ni * 16 + l16) * LDT + quad * 8]);
#pragma unroll
        for (int mi = 0; mi < 4; mi++)
#pragma unroll
            for (int ni = 0; ni < 4; ni++)
                acc[mi][ni] = __builtin_amdgcn_mfma_f32_16x16x32_bf16(af[mi], bfr[ni], acc[mi][ni], 0, 0, 0);
        __syncthreads();
    }

#pragma unroll
    for (int mi = 0; mi < 4; mi++) {
#pragma unroll
        for (int ni = 0; ni < 4; ni++) {
            int col = bn0 + wc * 64 + ni * 16 + l16;
#pragma unroll
            for (int r = 0; r < 4; r++) {
                int row = bm0 + wr * 64 + mi * 16 + quad * 4 + r;
                if (row < NN)
                    hb[(size_t)row * HC + col] = f2bf(acc[mi][ni][r]);
            }
        }
    }
}

// ---------------- scan1: per-block inclusive scan + block totals ----------------
__global__ __launch_bounds__(256) void scan1(const int* __restrict__ deg,
                                             int* __restrict__ tmp, int* __restrict__ bsum)
{
    __shared__ int s[256];
    int i = blockIdx.x * 256 + threadIdx.x;
    int v = (i < NN) ? deg[i] : 0;
    s[threadIdx.x] = v;
    __syncthreads();
    for (int off = 1; off < 256; off <<= 1) {
        int add = (threadIdx.x >= off) ? s[threadIdx.x - off] : 0;
        __syncthreads();
        s[threadIdx.x] += add;
        __syncthreads();
    }
    if (i < NN) tmp[i] = s[threadIdx.x];
    if (threadIdx.x == 255) bsum[blockIdx.x] = s[255];
}

// ---------------- scan2+scan3 fused ----------------
__global__ __launch_bounds__(256) void scan23(const int* __restrict__ deg,
                                              const int* __restrict__ tmp,
                                              const int* __restrict__ bsum,
                                              int* __restrict__ rowstart)
{
    __shared__ int s[256];
    int b = blockIdx.x, t = threadIdx.x;
    int v = (t < NB_SCAN && t < b) ? bsum[t] : 0;
    s[t] = v;
    __syncthreads();
#pragma unroll
    for (int off = 128; off > 0; off >>= 1) {
        if (t < off) s[t] += s[t + off];
        __syncthreads();
    }
    int offset = s[0];
    int i = b * 256 + t;
    if (i < NN) rowstart[i] = tmp[i] - deg[i] + offset;
    if (i == 0) rowstart[NN] = ET;
}

// ---------------- gather-aggregate: wave-per-node, half-wave edges, 4 gathers in flight ----
// NOTE: no dynamic register indexing (R5: compiler spills via LDS scratch).
__global__ __launch_bounds__(256) void agg7_kernel(const unsigned short* __restrict__ hb,
                                                   const int* __restrict__ rowstart,
                                                   const uint2* __restrict__ rec,
                                                   const float* __restrict__ bias,
                                                   unsigned short* __restrict__ aggb)
{
    int wave = threadIdx.x >> 6, lane = threadIdx.x & 63;
    int d = blockIdx.x * 4 + wave;
    int half = lane >> 5;
    int l = lane & 31;
    int hshift = (l >> 4) << 4;
    int c = l * 8;
    int j0 = rowstart[d], j1 = rowstart[d + 1];

    float a0 = 0.f, a1 = 0.f, a2 = 0.f, a3 = 0.f;
    float a4 = 0.f, a5 = 0.f, a6 = 0.f, a7 = 0.f;
    float psum = 0.f;

    int j = j0 + half;
    // 4 edges per half per iter = 8 edges/wave-iter, 4 gathers in flight
    for (; j + 6 < j1; j += 8) {
        uint2 r0 = rec[j], r1 = rec[j + 2], r2 = rec[j + 4], r3 = rec[j + 6];
        float p0 = h2f_bits((unsigned short)(r0.y >> hshift));
        float p1 = h2f_bits((unsigned short)(r1.y >> hshift));
        float p2 = h2f_bits((unsigned short)(r2.y >> hshift));
        float p3 = h2f_bits((unsigned short)(r3.y >> hshift));
        psum += p0 + p1 + p2 + p3;
        uint4 h0 = *(const uint4*)(hb + (size_t)r0.x * HC + c);
        uint4 h1 = *(const uint4*)(hb + (size_t)r1.x * HC + c);
        uint4 h2 = *(const uint4*)(hb + (size_t)r2.x * HC + c);
        uint4 h3 = *(const uint4*)(hb + (size_t)r3.x * HC + c);
        a0 += p0 * bf_lo(h0.x) + p1 * bf_lo(h1.x) + p2 * bf_lo(h2.x) + p3 * bf_lo(h3.x);
        a1 += p0 * bf_hi(h0.x) + p1 * bf_hi(h1.x) + p2 * bf_hi(h2.x) + p3 * bf_hi(h3.x);
        a2 += p0 * bf_lo(h0.y) + p1 * bf_lo(h1.y) + p2 * bf_lo(h2.y) + p3 * bf_lo(h3.y);
        a3 += p0 * bf_hi(h0.y) + p1 * bf_hi(h1.y) + p2 * bf_hi(h2.y) + p3 * bf_hi(h3.y);
        a4 += p0 * bf_lo(h0.z) + p1 * bf_lo(h1.z) + p2 * bf_lo(h2.z) + p3 * bf_lo(h3.z);
        a5 += p0 * bf_hi(h0.z) + p1 * bf_hi(h1.z) + p2 * bf_hi(h2.z) + p3 * bf_hi(h3.z);
        a6 += p0 * bf_lo(h0.w) + p1 * bf_lo(h1.w) + p2 * bf_lo(h2.w) + p3 * bf_lo(h3.w);
        a7 += p0 * bf_hi(h0.w) + p1 * bf_hi(h1.w) + p2 * bf_hi(h2.w) + p3 * bf_hi(h3.w);
    }
    for (; j < j1; j += 2) {
        uint2 r0 = rec[j];
        float p0 = h2f_bits((unsigned short)(r0.y >> hshift));
        psum += p0;
        uint4 h0 = *(const uint4*)(hb + (size_t)r0.x * HC + c);
        a0 += p0 * bf_lo(h0.x);
        a1 += p0 * bf_hi(h0.x);
        a2 += p0 * bf_lo(h0.y);
        a3 += p0 * bf_hi(h0.y);
        a4 += p0 * bf_lo(h0.z);
        a5 += p0 * bf_hi(h0.z);
        a6 += p0 * bf_lo(h0.w);
        a7 += p0 * bf_hi(h0.w);
    }

    a0 += __shfl_xor(a0, 32);
    a1 += __shfl_xor(a1, 32);
    a2 += __shfl_xor(a2, 32);
    a3 += __shfl_xor(a3, 32);
    a4 += __shfl_xor(a4, 32);
    a5 += __shfl_xor(a5, 32);
    a6 += __shfl_xor(a6, 32);
    a7 += __shfl_xor(a7, 32);
    psum += __shfl_xor(psum, 32);

    if (half == 0) {
        float inv = 1.f / fmaxf(psum, 1e-16f);
        float4 b0 = *(const float4*)(bias + c);
        float4 b1 = *(const float4*)(bias + c + 4);
        float v0 = a0 * inv + b0.x;
        float v1 = a1 * inv + b0.y;
        float v2 = a2 * inv + b0.z;
        float v3 = a3 * inv + b0.w;
        float v4 = a4 * inv + b1.x;
        float v5 = a5 * inv + b1.y;
        float v6 = a6 * inv + b1.z;
        float v7 = a7 * inv + b1.w;
        v0 = v0 > 0.f ? v0 : expm1f(v0);
        v1 = v1 > 0.f ? v1 : expm1f(v1);
        v2 = v2 > 0.f ? v2 : expm1f(v2);
        v3 = v3 > 0.f ? v3 : expm1f(v3);
        v4 = v4 > 0.f ? v4 : expm1f(v4);
        v5 = v5 > 0.f ? v5 : expm1f(v5);
        v6 = v6 > 0.f ? v6 : expm1f(v6);
        v7 = v7 > 0.f ? v7 : expm1f(v7);
        uint4 o;
        o.x = (unsigned int)f2bf(v0) | ((unsigned int)f2bf(v1) << 16);
        o.y = (unsigned int)f2bf(v2) | ((unsigned int)f2bf(v3) << 16);
        o.z = (unsigned int)f2bf(v4) | ((unsigned int)f2bf(v5) << 16);
        o.w = (unsigned int)f2bf(v6) | ((unsigned int)f2bf(v7) << 16);
        *(uint4*)(aggb + (size_t)d * HC + c) = o;
    }
}

// ---------------- launch ----------------
extern "C" void kernel_launch(void* const* d_in, const int* in_sizes, int n_in,
                              void* d_out, int out_size, void* d_ws, size_t ws_size,
                              hipStream_t stream)
{
    const float* x       = (const float*)d_in[0];
    const int*   ei32    = (const int*)d_in[1];
    const float* W       = (const float*)d_in[2];
    const float* att_src = (const float*)d_in[3];
    const float* att_dst = (const float*)d_in[4];
    const float* bias    = (const float*)d_in[5];
    const float* lin_w   = (const float*)d_in[6];
    const float* lin_b   = (const float*)d_in[7];
    float* out = (float*)d_out;

    char* ws = (char*)d_ws;
    size_t off = 0;
    auto alloc = [&](size_t bytes) -> void* {
        void* p = ws + off;
        off += (bytes + 255) & ~(size_t)255;
        return p;
    };

    // zero-init region first (deg only)
    int*   deg    = (int*)alloc((size_t)NN * 4);
    size_t zero_bytes = off;

    int*   flag     = (int*)alloc(256);
    int*   tmp      = (int*)alloc((size_t)NN * 4);
    int*   bsum     = (int*)alloc(1024);
    int*   rowstart = (int*)alloc((size_t)(NN + 1) * 4);
    int*   eord     = (int*)alloc((size_t)ET * 4);
    float* was      = (float*)alloc((size_t)HH * FIN * 4);
    float* wad      = (float*)alloc((size_t)HH * FIN * 4);
    float* a_s      = (float*)alloc((size_t)NN * 2 * 4);
    float* a_d      = (float*)alloc((size_t)NN * 2 * 4);
    uint2* rec      = (uint2*)alloc((size_t)ET * 8);
    unsigned short* xb     = (unsigned short*)alloc((size_t)NN * FIN * 2);
    unsigned short* Wb     = (unsigned short*)alloc((size_t)HC * FIN * 2);
    unsigned short* linwb  = (unsigned short*)alloc((size_t)CCOUT * HC * 2);
    unsigned short* hb     = (unsigned short*)alloc((size_t)NN * HC * 2);
    unsigned short* aggb   = (unsigned short*)alloc((size_t)NN * HC * 2);

    hipMemsetAsync(d_ws, 0, zero_bytes, stream);

    prep_kernel<<<PREP_GRID, 256, 0, stream>>>(W, att_src, att_dst, lin_w, ei32,
                                               was, wad, Wb, linwb, flag);

    xprep_count_kernel<<<NB_XPREP + NB_EDGE4, 256, 0, stream>>>(x, was, wad, xb, a_s, a_d,
                                                                ei32, flag, deg, eord);

    scan1<<<NB_SCAN, 256, 0, stream>>>(deg, tmp, bsum);
    scan23<<<NB_SCAN, 256, 0, stream>>>(deg, tmp, bsum, rowstart);

    scatter_gemm1_kernel<<<NB_FUSE, 256, 0, stream>>>(ei32, flag, eord, rowstart,
                                                      a_s, a_d, rec, xb, Wb, hb);

    agg7_kernel<<<NN / 4, 256, 0, stream>>>(hb, rowstart, rec, bias, aggb);

    dim3 g2((NN + 127) / 128, CCOUT / 128);
    gemm_mfma<true, false><<<g2, 256, 0, stream>>>(aggb, linwb, lin_b, out, NN, CCOUT, HC);
}